// Round 3
// baseline (207.962 us; speedup 1.0000x reference)
//
#include <hip/hip_runtime.h>
#include <math.h>

// BioTripletLoss: B=16384 rows, D=1024 fp32.
// pos_dist[i] = ||h[i]+r[i]-t[i]||, neg_dist[i] = ||h[i]+r[i]-t[neg_idx[i]]||
// dissim (rel==1): relu(0.6 - pos) + 0.5*exp(-pos)
// sim:             relu(pos - neg + 0.3) + 0.3*relu(0.1 - pos)
// out = mean(per_sample)
//
// R3: force memory-level parallelism. R1/R2 showed the compiler compresses
// to 28-32 VGPRs (max-occupancy scheduling) leaving ~2 loads in flight ->
// latency-bound at 3.4 TB/s effective. Fix: __launch_bounds__(256,2) to
// raise the register budget, explicit float4 register arrays so all 16
// loads issue before any consumption, gather loads issued right after the
// index arrives, pos-part computed while gather is in flight.

#define BDIM 16384
#define DDIM 1024

__global__ void zero_out_kernel(float* __restrict__ out) { out[0] = 0.0f; }

__global__ __launch_bounds__(256, 2) void triplet_fused_kernel(
    const float* __restrict__ h, const float* __restrict__ t,
    const float* __restrict__ r, const int* __restrict__ rel,
    const int* __restrict__ neg, float* __restrict__ out)
{
    const int wave = threadIdx.x >> 6;
    const int lane = threadIdx.x & 63;
    const int row  = (blockIdx.x << 2) + wave;

    // issue index/relation loads first (tiny, needed for gather address)
    const int nidx = neg[row];
    const int rl   = rel[row];

    const float4* h4 = (const float4*)(h + (size_t)row * DDIM);
    const float4* r4 = (const float4*)(r + (size_t)row * DDIM);
    const float4* t4 = (const float4*)(t + (size_t)row * DDIM);

    // 12 independent streaming loads — issue all before any use
    float4 H[4], R[4], T[4];
#pragma unroll
    for (int j = 0; j < 4; ++j) H[j] = h4[lane + (j << 6)];
#pragma unroll
    for (int j = 0; j < 4; ++j) R[j] = r4[lane + (j << 6)];
#pragma unroll
    for (int j = 0; j < 4; ++j) T[j] = t4[lane + (j << 6)];

    // gather loads (longest latency path) — issue as soon as nidx is known
    const float4* n4 = (const float4*)(t + (size_t)nidx * DDIM);
    float4 N[4];
#pragma unroll
    for (int j = 0; j < 4; ++j) N[j] = n4[lane + (j << 6)];

    // pos-distance partials: consumes H,R,T while N is still in flight
    float4 HR[4];
    float psum = 0.0f;
#pragma unroll
    for (int j = 0; j < 4; ++j) {
        HR[j].x = H[j].x + R[j].x; HR[j].y = H[j].y + R[j].y;
        HR[j].z = H[j].z + R[j].z; HR[j].w = H[j].w + R[j].w;
        float dx = HR[j].x - T[j].x, dy = HR[j].y - T[j].y,
              dz = HR[j].z - T[j].z, dw = HR[j].w - T[j].w;
        psum += dx * dx + dy * dy + dz * dz + dw * dw;
    }

    float nsum = 0.0f;
#pragma unroll
    for (int j = 0; j < 4; ++j) {
        float ex = HR[j].x - N[j].x, ey = HR[j].y - N[j].y,
              ez = HR[j].z - N[j].z, ew = HR[j].w - N[j].w;
        nsum += ex * ex + ey * ey + ez * ez + ew * ew;
    }

    // wave-64 butterfly reduction
#pragma unroll
    for (int off = 32; off > 0; off >>= 1) {
        psum += __shfl_down(psum, off, 64);
        nsum += __shfl_down(nsum, off, 64);
    }

    __shared__ float sm[4];
    if (lane == 0) {
        float pos = sqrtf(psum);
        float negd = sqrtf(nsum);
        float loss;
        if (rl == 1) loss = fmaxf(0.6f - pos, 0.0f) + 0.5f * expf(-pos);
        else         loss = fmaxf(pos - negd + 0.3f, 0.0f)
                          + 0.3f * fmaxf(0.1f - pos, 0.0f);
        sm[wave] = loss;
    }
    __syncthreads();
    if (threadIdx.x == 0) {
        float blk = (sm[0] + sm[1] + sm[2] + sm[3]) * (1.0f / (float)BDIM);
        atomicAdd(out, blk);   // device-scope by default on CDNA
    }
}

extern "C" void kernel_launch(void* const* d_in, const int* in_sizes, int n_in,
                              void* d_out, int out_size, void* d_ws, size_t ws_size,
                              hipStream_t stream) {
    const float* h = (const float*)d_in[0];
    const float* t = (const float*)d_in[1];
    const float* r = (const float*)d_in[2];
    const int* rel = (const int*)d_in[3];
    const int* neg = (const int*)d_in[4];
    float* out = (float*)d_out;

    zero_out_kernel<<<1, 1, 0, stream>>>(out);
    triplet_fused_kernel<<<BDIM / 4, 256, 0, stream>>>(h, t, r, rel, neg, out);
}